// Round 6
// baseline (41.253 us; speedup 1.0000x reference)
//
#include <hip/hip_runtime.h>
#include <math.h>

#define D 64
#define NC 8
#define FK 8
#define NMIN 1440
#define TWO_PI_F 6.28318530717958647692f

// native clang vector (accepted by __builtin_nontemporal_*), layout == float4
typedef float f4 __attribute__((ext_vector_type(4)));

// ---------------------------------------------------------------------------
// Kernel 1: build per-minute Fourier table T[m][n][d] (1440 x 8 x 64 fp32).
// F(m,n,d) = a0[n,d] + sum_k cos(k*ang)*fa[n,k,d] + sin(k*ang)*fb[n,k,d],
// ang = m * 2pi/1439. One sincosf + Chebyshev recurrence for harmonics 2..8:
//   c_{k+1} = 2*c1*c_k - c_{k-1},  s_{k+1} = 2*c1*s_k - s_{k-1}
// ---------------------------------------------------------------------------
__global__ __launch_bounds__(256) void build_table_kernel(
    const float* __restrict__ a0,
    const float* __restrict__ fa,
    const float* __restrict__ fb,
    float* __restrict__ T)
{
    const int m = blockIdx.x;        // minute 0..1439
    const int t = threadIdx.x;       // 256 threads: 4 n-slots x 64 d
    const int d  = t & (D - 1);
    const int n0 = t >> 6;           // 0..3
    const float angle = (float)m * (TWO_PI_F / (float)(NMIN - 1));

    float c[FK], s[FK];
    float s1, c1;
    sincosf(angle, &s1, &c1);
    c[0] = c1; s[0] = s1;
    {
        const float tw = 2.0f * c1;
        float cp = 1.0f, sp = 0.0f;      // k-1 terms (k=0)
        float cc = c1, ss = s1;          // k terms   (k=1)
#pragma unroll
        for (int k = 1; k < FK; ++k) {
            const float cn = fmaf(tw, cc, -cp);
            const float sn = fmaf(tw, ss, -sp);
            cp = cc; sp = ss; cc = cn; ss = sn;
            c[k] = cc; s[k] = ss;
        }
    }

#pragma unroll
    for (int j = 0; j < 2; ++j) {
        const int n = n0 + 4 * j;
        float v = a0[n * D + d];
#pragma unroll
        for (int k = 0; k < FK; ++k) {
            v = fmaf(c[k], fa[(n * FK + k) * D + d], v);
            v = fmaf(s[k], fb[(n * FK + k) * D + d], v);
        }
        T[(m * NC + n) * D + d] = v;   // normal store: we WANT this in L2
    }
}

// ---------------------------------------------------------------------------
// Kernel 2: 8 lanes per item. Lane j owns float4 d-slices j and j+8.
//  - emb read:    2 NT f4 loads, each instruction a contiguous 128B sweep
//  - scores:      per-lane partial dot (8 elems/cluster), shfl_xor reduce x3
//  - softmax(8):  redundant in all 8 lanes, registers only
//  - T gather:    16 f4 loads from L2-resident table, coalesced 256B rows
//  - outputs:     NT stores (stream-once; keep L2 for T/proto)
// ---------------------------------------------------------------------------
__global__ __launch_bounds__(256) void mix_kernel8(
    const float* __restrict__ emb,
    const float* __restrict__ thetas,
    const float* __restrict__ proto,
    const float* __restrict__ T,
    float* __restrict__ out_emb,
    float* __restrict__ out_P,
    int B)
{
    const int t = blockIdx.x * 256 + threadIdx.x;
    const int b = t >> 3;            // item index
    const int j = t & 7;             // lane-in-group
    if (b >= B) return;

    // --- minute bucket first so T addresses are known early ---
    const float th = thetas[b];                  // broadcast within group
    int m = (int)((th / TWO_PI_F) * (float)NMIN);
    m = m < 0 ? 0 : (m > NMIN - 1 ? NMIN - 1 : m);

    // --- emb slices (non-temporal: stream once) ---
    const f4* __restrict__ e4 = (const f4*)emb + (size_t)b * (D / 4);
    const f4 ev0 = __builtin_nontemporal_load(&e4[j]);
    const f4 ev1 = __builtin_nontemporal_load(&e4[j + 8]);

    // --- partial scores vs 8 prototypes (proto is 2KB, cache-hot) ---
    const f4* __restrict__ p4 = (const f4*)proto;
    float sc[NC];
#pragma unroll
    for (int n = 0; n < NC; ++n) {
        const f4 pa = p4[n * (D / 4) + j];
        const f4 pb = p4[n * (D / 4) + j + 8];
        float v = ev0.x * pa.x;
        v = fmaf(ev0.y, pa.y, v);
        v = fmaf(ev0.z, pa.z, v);
        v = fmaf(ev0.w, pa.w, v);
        v = fmaf(ev1.x, pb.x, v);
        v = fmaf(ev1.y, pb.y, v);
        v = fmaf(ev1.z, pb.z, v);
        v = fmaf(ev1.w, pb.w, v);
        sc[n] = v;
    }

    // --- reduce each score across the 8-lane group ---
#pragma unroll
    for (int n = 0; n < NC; ++n) {
        float v = sc[n];
        v += __shfl_xor(v, 1);
        v += __shfl_xor(v, 2);
        v += __shfl_xor(v, 4);
        sc[n] = v;
    }

    // --- softmax(scores / tau), tau = 0.2 -> *5 ---
    float mx = -1e30f;
#pragma unroll
    for (int n = 0; n < NC; ++n) { sc[n] *= 5.0f; mx = fmaxf(mx, sc[n]); }
    float sum = 0.0f;
#pragma unroll
    for (int n = 0; n < NC; ++n) { sc[n] = __expf(sc[n] - mx); sum += sc[n]; }
    const float inv = 1.0f / sum;
#pragma unroll
    for (int n = 0; n < NC; ++n) sc[n] *= inv;

    // --- gather T[m] rows (L2-resident, coalesced) and mix ---
    const f4* __restrict__ t4 = (const f4*)(T + (size_t)m * NC * D);
    f4 acc0 = (f4)(0.0f);
    f4 acc1 = (f4)(0.0f);
#pragma unroll
    for (int n = 0; n < NC; ++n) {
        const f4 ta = t4[n * (D / 4) + j];
        const f4 tb = t4[n * (D / 4) + j + 8];
        const float pw = sc[n];
        acc0.x = fmaf(pw, ta.x, acc0.x);
        acc0.y = fmaf(pw, ta.y, acc0.y);
        acc0.z = fmaf(pw, ta.z, acc0.z);
        acc0.w = fmaf(pw, ta.w, acc0.w);
        acc1.x = fmaf(pw, tb.x, acc1.x);
        acc1.y = fmaf(pw, tb.y, acc1.y);
        acc1.z = fmaf(pw, tb.z, acc1.z);
        acc1.w = fmaf(pw, tb.w, acc1.w);
    }

    f4* __restrict__ o4 = (f4*)out_emb + (size_t)b * (D / 4);
    __builtin_nontemporal_store(acc0, &o4[j]);
    __builtin_nontemporal_store(acc1, &o4[j + 8]);

    // --- P output: lanes 0 and 4 each write one f4 ---
    if (j == 0) {
        f4 pv; pv.x = sc[0]; pv.y = sc[1]; pv.z = sc[2]; pv.w = sc[3];
        __builtin_nontemporal_store(pv, &((f4*)out_P)[(size_t)b * 2 + 0]);
    } else if (j == 4) {
        f4 pv; pv.x = sc[4]; pv.y = sc[5]; pv.z = sc[6]; pv.w = sc[7];
        __builtin_nontemporal_store(pv, &((f4*)out_P)[(size_t)b * 2 + 1]);
    }
}

// ---------------------------------------------------------------------------
// Fallback (only if ws_size < 3 MB): fully fused, coefficients staged in LDS.
// ---------------------------------------------------------------------------
__global__ __launch_bounds__(256) void fused_fallback(
    const float* __restrict__ emb,
    const float* __restrict__ thetas,
    const float* __restrict__ proto,
    const float* __restrict__ a0,
    const float* __restrict__ fa,
    const float* __restrict__ fb,
    float* __restrict__ out_emb,
    float* __restrict__ out_P,
    int B)
{
    __shared__ float sp[NC * D];
    __shared__ float sa0[NC * D];
    __shared__ float sfa[NC * FK * D];
    __shared__ float sfb[NC * FK * D];
    for (int i = threadIdx.x; i < NC * D; i += 256) { sp[i] = proto[i]; sa0[i] = a0[i]; }
    for (int i = threadIdx.x; i < NC * FK * D; i += 256) { sfa[i] = fa[i]; sfb[i] = fb[i]; }
    __syncthreads();

    const int b = blockIdx.x * 256 + threadIdx.x;
    if (b >= B) return;

    const float4* __restrict__ e4  = (const float4*)(emb + (size_t)b * D);
    const float4* sp4  = (const float4*)sp;
    const float4* sa04 = (const float4*)sa0;
    const float4* sfa4 = (const float4*)sfa;
    const float4* sfb4 = (const float4*)sfb;

    float sc[NC];
#pragma unroll
    for (int n = 0; n < NC; ++n) sc[n] = 0.0f;
#pragma unroll
    for (int i = 0; i < D / 4; ++i) {
        const float4 ev = e4[i];
#pragma unroll
        for (int n = 0; n < NC; ++n) {
            const float4 pv = sp4[n * (D / 4) + i];
            sc[n] = fmaf(ev.x, pv.x, sc[n]);
            sc[n] = fmaf(ev.y, pv.y, sc[n]);
            sc[n] = fmaf(ev.z, pv.z, sc[n]);
            sc[n] = fmaf(ev.w, pv.w, sc[n]);
        }
    }
    float mx = -1e30f;
#pragma unroll
    for (int n = 0; n < NC; ++n) { sc[n] *= 5.0f; mx = fmaxf(mx, sc[n]); }
    float sum = 0.0f;
#pragma unroll
    for (int n = 0; n < NC; ++n) { sc[n] = __expf(sc[n] - mx); sum += sc[n]; }
    const float inv = 1.0f / sum;
#pragma unroll
    for (int n = 0; n < NC; ++n) sc[n] *= inv;

    const float th = thetas[b];
    int m = (int)((th / TWO_PI_F) * (float)NMIN);
    m = m < 0 ? 0 : (m > NMIN - 1 ? NMIN - 1 : m);
    const float angle = (float)m * (TWO_PI_F / (float)(NMIN - 1));
    float c[FK], s[FK];
#pragma unroll
    for (int k = 0; k < FK; ++k) sincosf(angle * (float)(k + 1), &s[k], &c[k]);

    float4 acc[D / 4];
#pragma unroll
    for (int i = 0; i < D / 4; ++i) acc[i] = make_float4(0.f, 0.f, 0.f, 0.f);
#pragma unroll
    for (int n = 0; n < NC; ++n) {
        const float pw = sc[n];
#pragma unroll
        for (int i = 0; i < D / 4; ++i) {
            float4 v = sa04[n * (D / 4) + i];
#pragma unroll
            for (int k = 0; k < FK; ++k) {
                const float4 av = sfa4[(n * FK + k) * (D / 4) + i];
                const float4 bv = sfb4[(n * FK + k) * (D / 4) + i];
                v.x = fmaf(c[k], av.x, v.x); v.x = fmaf(s[k], bv.x, v.x);
                v.y = fmaf(c[k], av.y, v.y); v.y = fmaf(s[k], bv.y, v.y);
                v.z = fmaf(c[k], av.z, v.z); v.z = fmaf(s[k], bv.z, v.z);
                v.w = fmaf(c[k], av.w, v.w); v.w = fmaf(s[k], bv.w, v.w);
            }
            acc[i].x = fmaf(pw, v.x, acc[i].x);
            acc[i].y = fmaf(pw, v.y, acc[i].y);
            acc[i].z = fmaf(pw, v.z, acc[i].z);
            acc[i].w = fmaf(pw, v.w, acc[i].w);
        }
    }
    float4* o4 = (float4*)(out_emb + (size_t)b * D);
#pragma unroll
    for (int i = 0; i < D / 4; ++i) o4[i] = acc[i];
    float4* op = (float4*)(out_P + (size_t)b * NC);
    op[0] = make_float4(sc[0], sc[1], sc[2], sc[3]);
    op[1] = make_float4(sc[4], sc[5], sc[6], sc[7]);
}

extern "C" void kernel_launch(void* const* d_in, const int* in_sizes, int n_in,
                              void* d_out, int out_size, void* d_ws, size_t ws_size,
                              hipStream_t stream)
{
    const float* emb    = (const float*)d_in[0];
    const float* thetas = (const float*)d_in[1];
    const float* proto  = (const float*)d_in[2];
    const float* a0     = (const float*)d_in[3];
    const float* fa     = (const float*)d_in[4];
    const float* fb     = (const float*)d_in[5];

    const int B = in_sizes[0] / D;           // 131072
    float* out_emb = (float*)d_out;
    float* out_P   = (float*)d_out + (size_t)B * D;

    const size_t table_bytes = (size_t)NMIN * NC * D * sizeof(float); // ~2.95 MB

    if (ws_size >= table_bytes) {
        float* T = (float*)d_ws;
        build_table_kernel<<<NMIN, 256, 0, stream>>>(a0, fa, fb, T);
        // 8 lanes per item: B*8 threads total
        const long long total_threads = (long long)B * 8;
        const int blocks = (int)((total_threads + 255) / 256);
        mix_kernel8<<<blocks, 256, 0, stream>>>(emb, thetas, proto, T, out_emb, out_P, B);
    } else {
        const int blocks = (B + 255) / 256;
        fused_fallback<<<blocks, 256, 0, stream>>>(emb, thetas, proto, a0, fa, fb,
                                                   out_emb, out_P, B);
    }
}

// Round 9
// 34.657 us; speedup vs baseline: 1.1903x; 1.1903x over previous
//
#include <hip/hip_runtime.h>
#include <math.h>

#define D 64
#define NC 8
#define FK 8
#define NMIN 1440
#define TWO_PI_F 6.28318530717958647692f

// ---------------------------------------------------------------------------
// Kernel 1: build per-minute Fourier table T[m][n][d] (1440 x 8 x 64 fp32).
// F(m,n,d) = a0[n,d] + sum_k cos(k*ang)*fa[n,k,d] + sin(k*ang)*fb[n,k,d],
// ang = m * 2pi/1439. One sincosf + Chebyshev recurrence for harmonics 2..8:
//   c_{k+1} = 2*c1*c_k - c_{k-1},  s_{k+1} = 2*c1*s_k - s_{k-1}
// ---------------------------------------------------------------------------
__global__ __launch_bounds__(256) void build_table_kernel(
    const float* __restrict__ a0,
    const float* __restrict__ fa,
    const float* __restrict__ fb,
    float* __restrict__ T)
{
    const int m = blockIdx.x;        // minute 0..1439
    const int t = threadIdx.x;       // 256 threads: 4 n-slots x 64 d
    const int d  = t & (D - 1);
    const int n0 = t >> 6;           // 0..3
    const float angle = (float)m * (TWO_PI_F / (float)(NMIN - 1));

    float c[FK], s[FK];
    float s1, c1;
    sincosf(angle, &s1, &c1);
    c[0] = c1; s[0] = s1;
    {
        const float tw = 2.0f * c1;
        float cp = 1.0f, sp = 0.0f;      // k-1 terms (k=0)
        float cc = c1, ss = s1;          // k terms   (k=1)
#pragma unroll
        for (int k = 1; k < FK; ++k) {
            const float cn = fmaf(tw, cc, -cp);
            const float sn = fmaf(tw, ss, -sp);
            cp = cc; sp = ss; cc = cn; ss = sn;
            c[k] = cc; s[k] = ss;
        }
    }

#pragma unroll
    for (int j = 0; j < 2; ++j) {
        const int n = n0 + 4 * j;
        float v = a0[n * D + d];
#pragma unroll
        for (int k = 0; k < FK; ++k) {
            v = fmaf(c[k], fa[(n * FK + k) * D + d], v);
            v = fmaf(s[k], fb[(n * FK + k) * D + d], v);
        }
        T[(m * NC + n) * D + d] = v;   // normal store: we WANT this in L2
    }
}

// ---------------------------------------------------------------------------
// Kernel 2 (round-4 proven version): 16 lanes per item. Lane i owns float4
// d-slice i (d = 4i..4i+3).
//  - emb read:   lane i loads emb[b][4i..4i+3]        -> 1KB/wave contiguous
//  - scores:     per-lane partial dot, shfl_xor reduce over the 16-lane group
//  - softmax(8)  computed redundantly in all 16 lanes (registers only)
//  - T gather:   lane i loads T[m][n][4i..4i+3], n=0..7 -> 256B/row coalesced
//  - mix + write: coalesced float4 stores
// ---------------------------------------------------------------------------
__global__ __launch_bounds__(256) void mix_kernel16(
    const float* __restrict__ emb,
    const float* __restrict__ thetas,
    const float* __restrict__ proto,
    const float* __restrict__ T,
    float* __restrict__ out_emb,
    float* __restrict__ out_P,
    int B)
{
    const int t = blockIdx.x * 256 + threadIdx.x;
    const int b = t >> 4;            // item index
    const int i = t & 15;            // d-slice index (float4 granularity)
    if (b >= B) return;

    // --- load this lane's emb slice (coalesced) ---
    const float4 ev = ((const float4*)emb)[(size_t)b * (D / 4) + i];

    // --- partial scores: sc[n] = dot(ev, proto[n][slice i]) ---
    const float4* __restrict__ p4 = (const float4*)proto;
    float sc[NC];
#pragma unroll
    for (int n = 0; n < NC; ++n) {
        const float4 pv = p4[n * (D / 4) + i];   // 2KB total, L1-resident
        float v = ev.x * pv.x;
        v = fmaf(ev.y, pv.y, v);
        v = fmaf(ev.z, pv.z, v);
        v = fmaf(ev.w, pv.w, v);
        sc[n] = v;
    }

    // --- reduce each score across the 16-lane group ---
#pragma unroll
    for (int n = 0; n < NC; ++n) {
        float v = sc[n];
        v += __shfl_xor(v, 1);
        v += __shfl_xor(v, 2);
        v += __shfl_xor(v, 4);
        v += __shfl_xor(v, 8);
        sc[n] = v;
    }

    // --- softmax(scores / tau), tau = 0.2 -> *5 (all lanes, registers only) ---
    float mx = -1e30f;
#pragma unroll
    for (int n = 0; n < NC; ++n) { sc[n] *= 5.0f; mx = fmaxf(mx, sc[n]); }
    float sum = 0.0f;
#pragma unroll
    for (int n = 0; n < NC; ++n) { sc[n] = __expf(sc[n] - mx); sum += sc[n]; }
    const float inv = 1.0f / sum;
#pragma unroll
    for (int n = 0; n < NC; ++n) sc[n] *= inv;

    // --- minute bucket (same op order as reference) ---
    const float th = thetas[b];                  // same addr across group -> bcast
    int m = (int)((th / TWO_PI_F) * (float)NMIN);
    m = m < 0 ? 0 : (m > NMIN - 1 ? NMIN - 1 : m);

    // --- gather T[m] rows (coalesced 256B per n) and mix ---
    const float4* __restrict__ t4 = (const float4*)(T + (size_t)m * NC * D);
    float4 acc = make_float4(0.f, 0.f, 0.f, 0.f);
#pragma unroll
    for (int n = 0; n < NC; ++n) {
        const float4 tv = t4[n * (D / 4) + i];
        const float pw = sc[n];
        acc.x = fmaf(pw, tv.x, acc.x);
        acc.y = fmaf(pw, tv.y, acc.y);
        acc.z = fmaf(pw, tv.z, acc.z);
        acc.w = fmaf(pw, tv.w, acc.w);
    }

    ((float4*)out_emb)[(size_t)b * (D / 4) + i] = acc;

    // --- P output: lanes 0 and 8 each write one float4 (compile-time select) ---
    if (i == 0) {
        ((float4*)out_P)[(size_t)b * 2 + 0] = make_float4(sc[0], sc[1], sc[2], sc[3]);
    } else if (i == 8) {
        ((float4*)out_P)[(size_t)b * 2 + 1] = make_float4(sc[4], sc[5], sc[6], sc[7]);
    }
}

// ---------------------------------------------------------------------------
// Fallback (only if ws_size < 3 MB): fully fused, coefficients staged in LDS.
// ---------------------------------------------------------------------------
__global__ __launch_bounds__(256) void fused_fallback(
    const float* __restrict__ emb,
    const float* __restrict__ thetas,
    const float* __restrict__ proto,
    const float* __restrict__ a0,
    const float* __restrict__ fa,
    const float* __restrict__ fb,
    float* __restrict__ out_emb,
    float* __restrict__ out_P,
    int B)
{
    __shared__ float sp[NC * D];
    __shared__ float sa0[NC * D];
    __shared__ float sfa[NC * FK * D];
    __shared__ float sfb[NC * FK * D];
    for (int i = threadIdx.x; i < NC * D; i += 256) { sp[i] = proto[i]; sa0[i] = a0[i]; }
    for (int i = threadIdx.x; i < NC * FK * D; i += 256) { sfa[i] = fa[i]; sfb[i] = fb[i]; }
    __syncthreads();

    const int b = blockIdx.x * 256 + threadIdx.x;
    if (b >= B) return;

    const float4* __restrict__ e4  = (const float4*)(emb + (size_t)b * D);
    const float4* sp4  = (const float4*)sp;
    const float4* sa04 = (const float4*)sa0;
    const float4* sfa4 = (const float4*)sfa;
    const float4* sfb4 = (const float4*)sfb;

    float sc[NC];
#pragma unroll
    for (int n = 0; n < NC; ++n) sc[n] = 0.0f;
#pragma unroll
    for (int i = 0; i < D / 4; ++i) {
        const float4 ev = e4[i];
#pragma unroll
        for (int n = 0; n < NC; ++n) {
            const float4 pv = sp4[n * (D / 4) + i];
            sc[n] = fmaf(ev.x, pv.x, sc[n]);
            sc[n] = fmaf(ev.y, pv.y, sc[n]);
            sc[n] = fmaf(ev.z, pv.z, sc[n]);
            sc[n] = fmaf(ev.w, pv.w, sc[n]);
        }
    }
    float mx = -1e30f;
#pragma unroll
    for (int n = 0; n < NC; ++n) { sc[n] *= 5.0f; mx = fmaxf(mx, sc[n]); }
    float sum = 0.0f;
#pragma unroll
    for (int n = 0; n < NC; ++n) { sc[n] = __expf(sc[n] - mx); sum += sc[n]; }
    const float inv = 1.0f / sum;
#pragma unroll
    for (int n = 0; n < NC; ++n) sc[n] *= inv;

    const float th = thetas[b];
    int m = (int)((th / TWO_PI_F) * (float)NMIN);
    m = m < 0 ? 0 : (m > NMIN - 1 ? NMIN - 1 : m);
    const float angle = (float)m * (TWO_PI_F / (float)(NMIN - 1));
    float c[FK], s[FK];
#pragma unroll
    for (int k = 0; k < FK; ++k) sincosf(angle * (float)(k + 1), &s[k], &c[k]);

    float4 acc[D / 4];
#pragma unroll
    for (int i = 0; i < D / 4; ++i) acc[i] = make_float4(0.f, 0.f, 0.f, 0.f);
#pragma unroll
    for (int n = 0; n < NC; ++n) {
        const float pw = sc[n];
#pragma unroll
        for (int i = 0; i < D / 4; ++i) {
            float4 v = sa04[n * (D / 4) + i];
#pragma unroll
            for (int k = 0; k < FK; ++k) {
                const float4 av = sfa4[(n * FK + k) * (D / 4) + i];
                const float4 bv = sfb4[(n * FK + k) * (D / 4) + i];
                v.x = fmaf(c[k], av.x, v.x); v.x = fmaf(s[k], bv.x, v.x);
                v.y = fmaf(c[k], av.y, v.y); v.y = fmaf(s[k], bv.y, v.y);
                v.z = fmaf(c[k], av.z, v.z); v.z = fmaf(s[k], bv.z, v.z);
                v.w = fmaf(c[k], av.w, v.w); v.w = fmaf(s[k], bv.w, v.w);
            }
            acc[i].x = fmaf(pw, v.x, acc[i].x);
            acc[i].y = fmaf(pw, v.y, acc[i].y);
            acc[i].z = fmaf(pw, v.z, acc[i].z);
            acc[i].w = fmaf(pw, v.w, acc[i].w);
        }
    }
    float4* o4 = (float4*)(out_emb + (size_t)b * D);
#pragma unroll
    for (int i = 0; i < D / 4; ++i) o4[i] = acc[i];
    float4* op = (float4*)(out_P + (size_t)b * NC);
    op[0] = make_float4(sc[0], sc[1], sc[2], sc[3]);
    op[1] = make_float4(sc[4], sc[5], sc[6], sc[7]);
}

extern "C" void kernel_launch(void* const* d_in, const int* in_sizes, int n_in,
                              void* d_out, int out_size, void* d_ws, size_t ws_size,
                              hipStream_t stream)
{
    const float* emb    = (const float*)d_in[0];
    const float* thetas = (const float*)d_in[1];
    const float* proto  = (const float*)d_in[2];
    const float* a0     = (const float*)d_in[3];
    const float* fa     = (const float*)d_in[4];
    const float* fb     = (const float*)d_in[5];

    const int B = in_sizes[0] / D;           // 131072
    float* out_emb = (float*)d_out;
    float* out_P   = (float*)d_out + (size_t)B * D;

    const size_t table_bytes = (size_t)NMIN * NC * D * sizeof(float); // ~2.95 MB

    if (ws_size >= table_bytes) {
        float* T = (float*)d_ws;
        build_table_kernel<<<NMIN, 256, 0, stream>>>(a0, fa, fb, T);
        // 16 lanes per item: B*16 threads total
        const long long total_threads = (long long)B * 16;
        const int blocks = (int)((total_threads + 255) / 256);
        mix_kernel16<<<blocks, 256, 0, stream>>>(emb, thetas, proto, T, out_emb, out_P, B);
    } else {
        const int blocks = (B + 255) / 256;
        fused_fallback<<<blocks, 256, 0, stream>>>(emb, thetas, proto, a0, fa, fb,
                                                   out_emb, out_P, B);
    }
}

// Round 10
// 31.725 us; speedup vs baseline: 1.3003x; 1.0924x over previous
//
#include <hip/hip_runtime.h>
#include <math.h>

#define D 64
#define NC 8
#define FK 8
#define NMIN 1440
#define TWO_PI_F 6.28318530717958647692f

// ---------------------------------------------------------------------------
// Kernel 1: build per-minute Fourier table T[m][n][d] (1440 x 8 x 64 fp32).
// One sincosf + Chebyshev recurrence (measured ~1-2us total).
// ---------------------------------------------------------------------------
__global__ __launch_bounds__(256) void build_table_kernel(
    const float* __restrict__ a0,
    const float* __restrict__ fa,
    const float* __restrict__ fb,
    float* __restrict__ T)
{
    const int m = blockIdx.x;        // minute 0..1439
    const int t = threadIdx.x;       // 256 threads: 4 n-slots x 64 d
    const int d  = t & (D - 1);
    const int n0 = t >> 6;           // 0..3
    const float angle = (float)m * (TWO_PI_F / (float)(NMIN - 1));

    float c[FK], s[FK];
    float s1, c1;
    sincosf(angle, &s1, &c1);
    c[0] = c1; s[0] = s1;
    {
        const float tw = 2.0f * c1;
        float cp = 1.0f, sp = 0.0f;
        float cc = c1, ss = s1;
#pragma unroll
        for (int k = 1; k < FK; ++k) {
            const float cn = fmaf(tw, cc, -cp);
            const float sn = fmaf(tw, ss, -sp);
            cp = cc; sp = ss; cc = cn; ss = sn;
            c[k] = cc; s[k] = ss;
        }
    }

#pragma unroll
    for (int j = 0; j < 2; ++j) {
        const int n = n0 + 4 * j;
        float v = a0[n * D + d];
#pragma unroll
        for (int k = 0; k < FK; ++k) {
            v = fmaf(c[k], fa[(n * FK + k) * D + d], v);
            v = fmaf(s[k], fb[(n * FK + k) * D + d], v);
        }
        T[(m * NC + n) * D + d] = v;
    }
}

// ---------------------------------------------------------------------------
// Kernel 2: 16 lanes per item; proto staged in LDS (single change vs round 9).
// Removes 268 MB of redundant proto traffic from the L1/VMEM pipe (each of 2M
// threads re-loaded 128B of the same 2KB array) -> moved to the LDS pipe.
// ---------------------------------------------------------------------------
__global__ __launch_bounds__(256) void mix_kernel16(
    const float* __restrict__ emb,
    const float* __restrict__ thetas,
    const float* __restrict__ proto,
    const float* __restrict__ T,
    float* __restrict__ out_emb,
    float* __restrict__ out_P,
    int B)
{
    __shared__ float4 sproto[NC * (D / 4)];      // 2 KB
    if (threadIdx.x < NC * (D / 4)) {            // 128 threads stage 1 float4 each
        sproto[threadIdx.x] = ((const float4*)proto)[threadIdx.x];
    }
    __syncthreads();

    const int t = blockIdx.x * 256 + threadIdx.x;
    const int b = t >> 4;            // item index
    const int i = t & 15;            // d-slice index (float4 granularity)
    if (b >= B) return;              // grid is exact (B*16 % 256 == 0); safe after sync

    // --- load this lane's emb slice (coalesced) ---
    const float4 ev = ((const float4*)emb)[(size_t)b * (D / 4) + i];

    // --- partial scores: sc[n] = dot(ev, proto[n][slice i]) from LDS ---
    float sc[NC];
#pragma unroll
    for (int n = 0; n < NC; ++n) {
        const float4 pv = sproto[n * (D / 4) + i];   // ds_read_b128, <=2-way alias (free)
        float v = ev.x * pv.x;
        v = fmaf(ev.y, pv.y, v);
        v = fmaf(ev.z, pv.z, v);
        v = fmaf(ev.w, pv.w, v);
        sc[n] = v;
    }

    // --- reduce each score across the 16-lane group ---
#pragma unroll
    for (int n = 0; n < NC; ++n) {
        float v = sc[n];
        v += __shfl_xor(v, 1);
        v += __shfl_xor(v, 2);
        v += __shfl_xor(v, 4);
        v += __shfl_xor(v, 8);
        sc[n] = v;
    }

    // --- softmax(scores / tau), tau = 0.2 -> *5 (all lanes, registers only) ---
    float mx = -1e30f;
#pragma unroll
    for (int n = 0; n < NC; ++n) { sc[n] *= 5.0f; mx = fmaxf(mx, sc[n]); }
    float sum = 0.0f;
#pragma unroll
    for (int n = 0; n < NC; ++n) { sc[n] = __expf(sc[n] - mx); sum += sc[n]; }
    const float inv = 1.0f / sum;
#pragma unroll
    for (int n = 0; n < NC; ++n) sc[n] *= inv;

    // --- minute bucket (same op order as reference) ---
    const float th = thetas[b];                  // same addr across group -> bcast
    int m = (int)((th / TWO_PI_F) * (float)NMIN);
    m = m < 0 ? 0 : (m > NMIN - 1 ? NMIN - 1 : m);

    // --- gather T[m] rows (coalesced 256B per n) and mix ---
    const float4* __restrict__ t4 = (const float4*)(T + (size_t)m * NC * D);
    float4 acc = make_float4(0.f, 0.f, 0.f, 0.f);
#pragma unroll
    for (int n = 0; n < NC; ++n) {
        const float4 tv = t4[n * (D / 4) + i];
        const float pw = sc[n];
        acc.x = fmaf(pw, tv.x, acc.x);
        acc.y = fmaf(pw, tv.y, acc.y);
        acc.z = fmaf(pw, tv.z, acc.z);
        acc.w = fmaf(pw, tv.w, acc.w);
    }

    ((float4*)out_emb)[(size_t)b * (D / 4) + i] = acc;

    // --- P output: lanes 0 and 8 each write one float4 ---
    if (i == 0) {
        ((float4*)out_P)[(size_t)b * 2 + 0] = make_float4(sc[0], sc[1], sc[2], sc[3]);
    } else if (i == 8) {
        ((float4*)out_P)[(size_t)b * 2 + 1] = make_float4(sc[4], sc[5], sc[6], sc[7]);
    }
}

// ---------------------------------------------------------------------------
// Fallback (only if ws_size < 3 MB): fully fused, coefficients staged in LDS.
// ---------------------------------------------------------------------------
__global__ __launch_bounds__(256) void fused_fallback(
    const float* __restrict__ emb,
    const float* __restrict__ thetas,
    const float* __restrict__ proto,
    const float* __restrict__ a0,
    const float* __restrict__ fa,
    const float* __restrict__ fb,
    float* __restrict__ out_emb,
    float* __restrict__ out_P,
    int B)
{
    __shared__ float sp[NC * D];
    __shared__ float sa0[NC * D];
    __shared__ float sfa[NC * FK * D];
    __shared__ float sfb[NC * FK * D];
    for (int i = threadIdx.x; i < NC * D; i += 256) { sp[i] = proto[i]; sa0[i] = a0[i]; }
    for (int i = threadIdx.x; i < NC * FK * D; i += 256) { sfa[i] = fa[i]; sfb[i] = fb[i]; }
    __syncthreads();

    const int b = blockIdx.x * 256 + threadIdx.x;
    if (b >= B) return;

    const float4* __restrict__ e4  = (const float4*)(emb + (size_t)b * D);
    const float4* sp4  = (const float4*)sp;
    const float4* sa04 = (const float4*)sa0;
    const float4* sfa4 = (const float4*)sfa;
    const float4* sfb4 = (const float4*)sfb;

    float sc[NC];
#pragma unroll
    for (int n = 0; n < NC; ++n) sc[n] = 0.0f;
#pragma unroll
    for (int i = 0; i < D / 4; ++i) {
        const float4 ev = e4[i];
#pragma unroll
        for (int n = 0; n < NC; ++n) {
            const float4 pv = sp4[n * (D / 4) + i];
            sc[n] = fmaf(ev.x, pv.x, sc[n]);
            sc[n] = fmaf(ev.y, pv.y, sc[n]);
            sc[n] = fmaf(ev.z, pv.z, sc[n]);
            sc[n] = fmaf(ev.w, pv.w, sc[n]);
        }
    }
    float mx = -1e30f;
#pragma unroll
    for (int n = 0; n < NC; ++n) { sc[n] *= 5.0f; mx = fmaxf(mx, sc[n]); }
    float sum = 0.0f;
#pragma unroll
    for (int n = 0; n < NC; ++n) { sc[n] = __expf(sc[n] - mx); sum += sc[n]; }
    const float inv = 1.0f / sum;
#pragma unroll
    for (int n = 0; n < NC; ++n) sc[n] *= inv;

    const float th = thetas[b];
    int m = (int)((th / TWO_PI_F) * (float)NMIN);
    m = m < 0 ? 0 : (m > NMIN - 1 ? NMIN - 1 : m);
    const float angle = (float)m * (TWO_PI_F / (float)(NMIN - 1));
    float c[FK], s[FK];
#pragma unroll
    for (int k = 0; k < FK; ++k) sincosf(angle * (float)(k + 1), &s[k], &c[k]);

    float4 acc[D / 4];
#pragma unroll
    for (int i = 0; i < D / 4; ++i) acc[i] = make_float4(0.f, 0.f, 0.f, 0.f);
#pragma unroll
    for (int n = 0; n < NC; ++n) {
        const float pw = sc[n];
#pragma unroll
        for (int i = 0; i < D / 4; ++i) {
            float4 v = sa04[n * (D / 4) + i];
#pragma unroll
            for (int k = 0; k < FK; ++k) {
                const float4 av = sfa4[(n * FK + k) * (D / 4) + i];
                const float4 bv = sfb4[(n * FK + k) * (D / 4) + i];
                v.x = fmaf(c[k], av.x, v.x); v.x = fmaf(s[k], bv.x, v.x);
                v.y = fmaf(c[k], av.y, v.y); v.y = fmaf(s[k], bv.y, v.y);
                v.z = fmaf(c[k], av.z, v.z); v.z = fmaf(s[k], bv.z, v.z);
                v.w = fmaf(c[k], av.w, v.w); v.w = fmaf(s[k], bv.w, v.w);
            }
            acc[i].x = fmaf(pw, v.x, acc[i].x);
            acc[i].y = fmaf(pw, v.y, acc[i].y);
            acc[i].z = fmaf(pw, v.z, acc[i].z);
            acc[i].w = fmaf(pw, v.w, acc[i].w);
        }
    }
    float4* o4 = (float4*)(out_emb + (size_t)b * D);
#pragma unroll
    for (int i = 0; i < D / 4; ++i) o4[i] = acc[i];
    float4* op = (float4*)(out_P + (size_t)b * NC);
    op[0] = make_float4(sc[0], sc[1], sc[2], sc[3]);
    op[1] = make_float4(sc[4], sc[5], sc[6], sc[7]);
}

extern "C" void kernel_launch(void* const* d_in, const int* in_sizes, int n_in,
                              void* d_out, int out_size, void* d_ws, size_t ws_size,
                              hipStream_t stream)
{
    const float* emb    = (const float*)d_in[0];
    const float* thetas = (const float*)d_in[1];
    const float* proto  = (const float*)d_in[2];
    const float* a0     = (const float*)d_in[3];
    const float* fa     = (const float*)d_in[4];
    const float* fb     = (const float*)d_in[5];

    const int B = in_sizes[0] / D;           // 131072
    float* out_emb = (float*)d_out;
    float* out_P   = (float*)d_out + (size_t)B * D;

    const size_t table_bytes = (size_t)NMIN * NC * D * sizeof(float); // ~2.95 MB

    if (ws_size >= table_bytes) {
        float* T = (float*)d_ws;
        build_table_kernel<<<NMIN, 256, 0, stream>>>(a0, fa, fb, T);
        // 16 lanes per item: B*16 threads total
        const long long total_threads = (long long)B * 16;
        const int blocks = (int)((total_threads + 255) / 256);
        mix_kernel16<<<blocks, 256, 0, stream>>>(emb, thetas, proto, T, out_emb, out_P, B);
    } else {
        const int blocks = (B + 255) / 256;
        fused_fallback<<<blocks, 256, 0, stream>>>(emb, thetas, proto, a0, fa, fb,
                                                   out_emb, out_P, B);
    }
}

// Round 11
// 31.373 us; speedup vs baseline: 1.3149x; 1.0112x over previous
//
#include <hip/hip_runtime.h>
#include <math.h>

#define D 64
#define NC 8
#define FK 8
#define NMIN 1440
#define TWO_PI_F 6.28318530717958647692f

// ---------------------------------------------------------------------------
// Kernel 1: build per-minute Fourier table T[m][n][d] (1440 x 8 x 64 fp32).
// One sincosf + Chebyshev recurrence (measured ~1-2us total).
// ---------------------------------------------------------------------------
__global__ __launch_bounds__(256) void build_table_kernel(
    const float* __restrict__ a0,
    const float* __restrict__ fa,
    const float* __restrict__ fb,
    float* __restrict__ T)
{
    const int m = blockIdx.x;        // minute 0..1439
    const int t = threadIdx.x;       // 256 threads: 4 n-slots x 64 d
    const int d  = t & (D - 1);
    const int n0 = t >> 6;           // 0..3
    const float angle = (float)m * (TWO_PI_F / (float)(NMIN - 1));

    float c[FK], s[FK];
    float s1, c1;
    sincosf(angle, &s1, &c1);
    c[0] = c1; s[0] = s1;
    {
        const float tw = 2.0f * c1;
        float cp = 1.0f, sp = 0.0f;
        float cc = c1, ss = s1;
#pragma unroll
        for (int k = 1; k < FK; ++k) {
            const float cn = fmaf(tw, cc, -cp);
            const float sn = fmaf(tw, ss, -sp);
            cp = cc; sp = ss; cc = cn; ss = sn;
            c[k] = cc; s[k] = ss;
        }
    }

#pragma unroll
    for (int j = 0; j < 2; ++j) {
        const int n = n0 + 4 * j;
        float v = a0[n * D + d];
#pragma unroll
        for (int k = 0; k < FK; ++k) {
            v = fmaf(c[k], fa[(n * FK + k) * D + d], v);
            v = fmaf(s[k], fb[(n * FK + k) * D + d], v);
        }
        T[(m * NC + n) * D + d] = v;
    }
}

// ---------------------------------------------------------------------------
// 16-lane all-reduce sum entirely on the VALU via DPP (zero DS-pipe ops):
//   xor1 = quad_perm(1,0,3,2)=0xB1, xor2 = quad_perm(2,3,0,1)=0x4E,
//   xor7 = row_half_mirror=0x141 (pairs opposite quads within 8),
//   xor8 = row_ror:8=0x128 (within the 16-lane DPP row).
// Groups are 16-lane aligned, so all patterns stay inside the group.
// ---------------------------------------------------------------------------
__device__ __forceinline__ float grp16_allreduce_sum(float v) {
    int t;
    t = __builtin_amdgcn_update_dpp(0, __float_as_int(v), 0xB1, 0xF, 0xF, true);
    v += __int_as_float(t);
    t = __builtin_amdgcn_update_dpp(0, __float_as_int(v), 0x4E, 0xF, 0xF, true);
    v += __int_as_float(t);
    t = __builtin_amdgcn_update_dpp(0, __float_as_int(v), 0x141, 0xF, 0xF, true);
    v += __int_as_float(t);
    t = __builtin_amdgcn_update_dpp(0, __float_as_int(v), 0x128, 0xF, 0xF, true);
    v += __int_as_float(t);
    return v;
}

// ---------------------------------------------------------------------------
// Kernel 2: 16 lanes per item; proto in LDS; DPP score reduction
// (single change vs round 10: shfl_xor butterfly -> DPP VALU reduction).
// ---------------------------------------------------------------------------
__global__ __launch_bounds__(256) void mix_kernel16(
    const float* __restrict__ emb,
    const float* __restrict__ thetas,
    const float* __restrict__ proto,
    const float* __restrict__ T,
    float* __restrict__ out_emb,
    float* __restrict__ out_P,
    int B)
{
    __shared__ float4 sproto[NC * (D / 4)];      // 2 KB
    if (threadIdx.x < NC * (D / 4)) {
        sproto[threadIdx.x] = ((const float4*)proto)[threadIdx.x];
    }
    __syncthreads();

    const int t = blockIdx.x * 256 + threadIdx.x;
    const int b = t >> 4;            // item index
    const int i = t & 15;            // d-slice index (float4 granularity)
    if (b >= B) return;

    // --- load this lane's emb slice (coalesced) ---
    const float4 ev = ((const float4*)emb)[(size_t)b * (D / 4) + i];

    // --- partial scores: sc[n] = dot(ev, proto[n][slice i]) from LDS ---
    float sc[NC];
#pragma unroll
    for (int n = 0; n < NC; ++n) {
        const float4 pv = sproto[n * (D / 4) + i];
        float v = ev.x * pv.x;
        v = fmaf(ev.y, pv.y, v);
        v = fmaf(ev.z, pv.z, v);
        v = fmaf(ev.w, pv.w, v);
        sc[n] = v;
    }

    // --- reduce each score across the 16-lane group (VALU/DPP, no DS ops) ---
#pragma unroll
    for (int n = 0; n < NC; ++n) {
        sc[n] = grp16_allreduce_sum(sc[n]);
    }

    // --- softmax(scores / tau), tau = 0.2 -> *5 (all lanes, registers only) ---
    float mx = -1e30f;
#pragma unroll
    for (int n = 0; n < NC; ++n) { sc[n] *= 5.0f; mx = fmaxf(mx, sc[n]); }
    float sum = 0.0f;
#pragma unroll
    for (int n = 0; n < NC; ++n) { sc[n] = __expf(sc[n] - mx); sum += sc[n]; }
    const float inv = 1.0f / sum;
#pragma unroll
    for (int n = 0; n < NC; ++n) sc[n] *= inv;

    // --- minute bucket (same op order as reference) ---
    const float th = thetas[b];                  // same addr across group -> bcast
    int m = (int)((th / TWO_PI_F) * (float)NMIN);
    m = m < 0 ? 0 : (m > NMIN - 1 ? NMIN - 1 : m);

    // --- gather T[m] rows (coalesced 256B per n) and mix ---
    const float4* __restrict__ t4 = (const float4*)(T + (size_t)m * NC * D);
    float4 acc = make_float4(0.f, 0.f, 0.f, 0.f);
#pragma unroll
    for (int n = 0; n < NC; ++n) {
        const float4 tv = t4[n * (D / 4) + i];
        const float pw = sc[n];
        acc.x = fmaf(pw, tv.x, acc.x);
        acc.y = fmaf(pw, tv.y, acc.y);
        acc.z = fmaf(pw, tv.z, acc.z);
        acc.w = fmaf(pw, tv.w, acc.w);
    }

    ((float4*)out_emb)[(size_t)b * (D / 4) + i] = acc;

    // --- P output: lanes 0 and 8 each write one float4 ---
    if (i == 0) {
        ((float4*)out_P)[(size_t)b * 2 + 0] = make_float4(sc[0], sc[1], sc[2], sc[3]);
    } else if (i == 8) {
        ((float4*)out_P)[(size_t)b * 2 + 1] = make_float4(sc[4], sc[5], sc[6], sc[7]);
    }
}

// ---------------------------------------------------------------------------
// Fallback (only if ws_size < 3 MB): fully fused, coefficients staged in LDS.
// ---------------------------------------------------------------------------
__global__ __launch_bounds__(256) void fused_fallback(
    const float* __restrict__ emb,
    const float* __restrict__ thetas,
    const float* __restrict__ proto,
    const float* __restrict__ a0,
    const float* __restrict__ fa,
    const float* __restrict__ fb,
    float* __restrict__ out_emb,
    float* __restrict__ out_P,
    int B)
{
    __shared__ float sp[NC * D];
    __shared__ float sa0[NC * D];
    __shared__ float sfa[NC * FK * D];
    __shared__ float sfb[NC * FK * D];
    for (int i = threadIdx.x; i < NC * D; i += 256) { sp[i] = proto[i]; sa0[i] = a0[i]; }
    for (int i = threadIdx.x; i < NC * FK * D; i += 256) { sfa[i] = fa[i]; sfb[i] = fb[i]; }
    __syncthreads();

    const int b = blockIdx.x * 256 + threadIdx.x;
    if (b >= B) return;

    const float4* __restrict__ e4  = (const float4*)(emb + (size_t)b * D);
    const float4* sp4  = (const float4*)sp;
    const float4* sa04 = (const float4*)sa0;
    const float4* sfa4 = (const float4*)sfa;
    const float4* sfb4 = (const float4*)sfb;

    float sc[NC];
#pragma unroll
    for (int n = 0; n < NC; ++n) sc[n] = 0.0f;
#pragma unroll
    for (int i = 0; i < D / 4; ++i) {
        const float4 ev = e4[i];
#pragma unroll
        for (int n = 0; n < NC; ++n) {
            const float4 pv = sp4[n * (D / 4) + i];
            sc[n] = fmaf(ev.x, pv.x, sc[n]);
            sc[n] = fmaf(ev.y, pv.y, sc[n]);
            sc[n] = fmaf(ev.z, pv.z, sc[n]);
            sc[n] = fmaf(ev.w, pv.w, sc[n]);
        }
    }
    float mx = -1e30f;
#pragma unroll
    for (int n = 0; n < NC; ++n) { sc[n] *= 5.0f; mx = fmaxf(mx, sc[n]); }
    float sum = 0.0f;
#pragma unroll
    for (int n = 0; n < NC; ++n) { sc[n] = __expf(sc[n] - mx); sum += sc[n]; }
    const float inv = 1.0f / sum;
#pragma unroll
    for (int n = 0; n < NC; ++n) sc[n] *= inv;

    const float th = thetas[b];
    int m = (int)((th / TWO_PI_F) * (float)NMIN);
    m = m < 0 ? 0 : (m > NMIN - 1 ? NMIN - 1 : m);
    const float angle = (float)m * (TWO_PI_F / (float)(NMIN - 1));
    float c[FK], s[FK];
#pragma unroll
    for (int k = 0; k < FK; ++k) sincosf(angle * (float)(k + 1), &s[k], &c[k]);

    float4 acc[D / 4];
#pragma unroll
    for (int i = 0; i < D / 4; ++i) acc[i] = make_float4(0.f, 0.f, 0.f, 0.f);
#pragma unroll
    for (int n = 0; n < NC; ++n) {
        const float pw = sc[n];
#pragma unroll
        for (int i = 0; i < D / 4; ++i) {
            float4 v = sa04[n * (D / 4) + i];
#pragma unroll
            for (int k = 0; k < FK; ++k) {
                const float4 av = sfa4[(n * FK + k) * (D / 4) + i];
                const float4 bv = sfb4[(n * FK + k) * (D / 4) + i];
                v.x = fmaf(c[k], av.x, v.x); v.x = fmaf(s[k], bv.x, v.x);
                v.y = fmaf(c[k], av.y, v.y); v.y = fmaf(s[k], bv.y, v.y);
                v.z = fmaf(c[k], av.z, v.z); v.z = fmaf(s[k], bv.z, v.z);
                v.w = fmaf(c[k], av.w, v.w); v.w = fmaf(s[k], bv.w, v.w);
            }
            acc[i].x = fmaf(pw, v.x, acc[i].x);
            acc[i].y = fmaf(pw, v.y, acc[i].y);
            acc[i].z = fmaf(pw, v.z, acc[i].z);
            acc[i].w = fmaf(pw, v.w, acc[i].w);
        }
    }
    float4* o4 = (float4*)(out_emb + (size_t)b * D);
#pragma unroll
    for (int i = 0; i < D / 4; ++i) o4[i] = acc[i];
    float4* op = (float4*)(out_P + (size_t)b * NC);
    op[0] = make_float4(sc[0], sc[1], sc[2], sc[3]);
    op[1] = make_float4(sc[4], sc[5], sc[6], sc[7]);
}

extern "C" void kernel_launch(void* const* d_in, const int* in_sizes, int n_in,
                              void* d_out, int out_size, void* d_ws, size_t ws_size,
                              hipStream_t stream)
{
    const float* emb    = (const float*)d_in[0];
    const float* thetas = (const float*)d_in[1];
    const float* proto  = (const float*)d_in[2];
    const float* a0     = (const float*)d_in[3];
    const float* fa     = (const float*)d_in[4];
    const float* fb     = (const float*)d_in[5];

    const int B = in_sizes[0] / D;           // 131072
    float* out_emb = (float*)d_out;
    float* out_P   = (float*)d_out + (size_t)B * D;

    const size_t table_bytes = (size_t)NMIN * NC * D * sizeof(float); // ~2.95 MB

    if (ws_size >= table_bytes) {
        float* T = (float*)d_ws;
        build_table_kernel<<<NMIN, 256, 0, stream>>>(a0, fa, fb, T);
        // 16 lanes per item: B*16 threads total
        const long long total_threads = (long long)B * 16;
        const int blocks = (int)((total_threads + 255) / 256);
        mix_kernel16<<<blocks, 256, 0, stream>>>(emb, thetas, proto, T, out_emb, out_P, B);
    } else {
        const int blocks = (B + 255) / 256;
        fused_fallback<<<blocks, 256, 0, stream>>>(emb, thetas, proto, a0, fa, fb,
                                                   out_emb, out_P, B);
    }
}

// Round 12
// 30.682 us; speedup vs baseline: 1.3445x; 1.0225x over previous
//
#include <hip/hip_runtime.h>
#include <math.h>

#define D 64
#define NC 8
#define FK 8
#define NMIN 1440
#define TWO_PI_F 6.28318530717958647692f

// ---------------------------------------------------------------------------
// Kernel 1: build per-minute Fourier table T[m][n][d] (1440 x 8 x 64 fp32).
// One sincosf + Chebyshev recurrence (measured ~1-2us total).
// ---------------------------------------------------------------------------
__global__ __launch_bounds__(256) void build_table_kernel(
    const float* __restrict__ a0,
    const float* __restrict__ fa,
    const float* __restrict__ fb,
    float* __restrict__ T)
{
    const int m = blockIdx.x;        // minute 0..1439
    const int t = threadIdx.x;       // 256 threads: 4 n-slots x 64 d
    const int d  = t & (D - 1);
    const int n0 = t >> 6;           // 0..3
    const float angle = (float)m * (TWO_PI_F / (float)(NMIN - 1));

    float c[FK], s[FK];
    float s1, c1;
    sincosf(angle, &s1, &c1);
    c[0] = c1; s[0] = s1;
    {
        const float tw = 2.0f * c1;
        float cp = 1.0f, sp = 0.0f;
        float cc = c1, ss = s1;
#pragma unroll
        for (int k = 1; k < FK; ++k) {
            const float cn = fmaf(tw, cc, -cp);
            const float sn = fmaf(tw, ss, -sp);
            cp = cc; sp = ss; cc = cn; ss = sn;
            c[k] = cc; s[k] = ss;
        }
    }

#pragma unroll
    for (int j = 0; j < 2; ++j) {
        const int n = n0 + 4 * j;
        float v = a0[n * D + d];
#pragma unroll
        for (int k = 0; k < FK; ++k) {
            v = fmaf(c[k], fa[(n * FK + k) * D + d], v);
            v = fmaf(s[k], fb[(n * FK + k) * D + d], v);
        }
        T[(m * NC + n) * D + d] = v;
    }
}

// ---------------------------------------------------------------------------
// 8-lane all-reduce sum on the VALU via DPP (groups are 8-lane aligned):
//   xor1 = quad_perm(1,0,3,2)=0xB1, xor2 = quad_perm(2,3,0,1)=0x4E,
//   cross-quad = row_half_mirror=0x141 (lane i <-> 7-i within each 8:
//   after the two quad_perm steps each lane holds its quad sum, and the
//   mirror always pairs opposite quads, completing the 8-lane sum).
// ---------------------------------------------------------------------------
__device__ __forceinline__ float grp8_allreduce_sum(float v) {
    int t;
    t = __builtin_amdgcn_update_dpp(0, __float_as_int(v), 0xB1, 0xF, 0xF, true);
    v += __int_as_float(t);
    t = __builtin_amdgcn_update_dpp(0, __float_as_int(v), 0x4E, 0xF, 0xF, true);
    v += __int_as_float(t);
    t = __builtin_amdgcn_update_dpp(0, __float_as_int(v), 0x141, 0xF, 0xF, true);
    v += __int_as_float(t);
    return v;
}

// ---------------------------------------------------------------------------
// Kernel 2: 8 lanes per item (single change vs round 11: 16 -> 8 lanes,
// isolating lane count from round-6's NT-load confound).
// Lane j owns float4 d-slices j and j+8. proto in LDS. DPP 3-step reduce.
// ---------------------------------------------------------------------------
__global__ __launch_bounds__(256) void mix_kernel8(
    const float* __restrict__ emb,
    const float* __restrict__ thetas,
    const float* __restrict__ proto,
    const float* __restrict__ T,
    float* __restrict__ out_emb,
    float* __restrict__ out_P,
    int B)
{
    __shared__ float4 sproto[NC * (D / 4)];      // 2 KB
    if (threadIdx.x < NC * (D / 4)) {
        sproto[threadIdx.x] = ((const float4*)proto)[threadIdx.x];
    }
    __syncthreads();

    const int t = blockIdx.x * 256 + threadIdx.x;
    const int b = t >> 3;            // item index
    const int j = t & 7;             // lane-in-group
    if (b >= B) return;

    // --- minute bucket early so T addresses are independent of the score chain ---
    const float th = thetas[b];                  // broadcast within group
    int m = (int)((th / TWO_PI_F) * (float)NMIN);
    m = m < 0 ? 0 : (m > NMIN - 1 ? NMIN - 1 : m);

    // --- emb slices (coalesced: each inst sweeps 128B per item, contiguous) ---
    const float4* __restrict__ e4 = (const float4*)emb + (size_t)b * (D / 4);
    const float4 ev0 = e4[j];
    const float4 ev1 = e4[j + 8];

    // --- partial scores vs 8 prototypes (from LDS) ---
    float sc[NC];
#pragma unroll
    for (int n = 0; n < NC; ++n) {
        const float4 pa = sproto[n * (D / 4) + j];
        const float4 pb = sproto[n * (D / 4) + j + 8];
        float v = ev0.x * pa.x;
        v = fmaf(ev0.y, pa.y, v);
        v = fmaf(ev0.z, pa.z, v);
        v = fmaf(ev0.w, pa.w, v);
        v = fmaf(ev1.x, pb.x, v);
        v = fmaf(ev1.y, pb.y, v);
        v = fmaf(ev1.z, pb.z, v);
        v = fmaf(ev1.w, pb.w, v);
        sc[n] = v;
    }

    // --- reduce each score across the 8-lane group (VALU/DPP) ---
#pragma unroll
    for (int n = 0; n < NC; ++n) {
        sc[n] = grp8_allreduce_sum(sc[n]);
    }

    // --- softmax(scores / tau), tau = 0.2 -> *5 ---
    float mx = -1e30f;
#pragma unroll
    for (int n = 0; n < NC; ++n) { sc[n] *= 5.0f; mx = fmaxf(mx, sc[n]); }
    float sum = 0.0f;
#pragma unroll
    for (int n = 0; n < NC; ++n) { sc[n] = __expf(sc[n] - mx); sum += sc[n]; }
    const float inv = 1.0f / sum;
#pragma unroll
    for (int n = 0; n < NC; ++n) sc[n] *= inv;

    // --- gather T[m] rows (coalesced 256B per n, L2-resident) and mix ---
    const float4* __restrict__ t4 = (const float4*)(T + (size_t)m * NC * D);
    float4 acc0 = make_float4(0.f, 0.f, 0.f, 0.f);
    float4 acc1 = make_float4(0.f, 0.f, 0.f, 0.f);
#pragma unroll
    for (int n = 0; n < NC; ++n) {
        const float4 ta = t4[n * (D / 4) + j];
        const float4 tb = t4[n * (D / 4) + j + 8];
        const float pw = sc[n];
        acc0.x = fmaf(pw, ta.x, acc0.x);
        acc0.y = fmaf(pw, ta.y, acc0.y);
        acc0.z = fmaf(pw, ta.z, acc0.z);
        acc0.w = fmaf(pw, ta.w, acc0.w);
        acc1.x = fmaf(pw, tb.x, acc1.x);
        acc1.y = fmaf(pw, tb.y, acc1.y);
        acc1.z = fmaf(pw, tb.z, acc1.z);
        acc1.w = fmaf(pw, tb.w, acc1.w);
    }

    float4* __restrict__ o4 = (float4*)out_emb + (size_t)b * (D / 4);
    o4[j]     = acc0;
    o4[j + 8] = acc1;

    // --- P output: lanes 0 and 4 each write one float4 ---
    if (j == 0) {
        ((float4*)out_P)[(size_t)b * 2 + 0] = make_float4(sc[0], sc[1], sc[2], sc[3]);
    } else if (j == 4) {
        ((float4*)out_P)[(size_t)b * 2 + 1] = make_float4(sc[4], sc[5], sc[6], sc[7]);
    }
}

// ---------------------------------------------------------------------------
// Fallback (only if ws_size < 3 MB): fully fused, coefficients staged in LDS.
// ---------------------------------------------------------------------------
__global__ __launch_bounds__(256) void fused_fallback(
    const float* __restrict__ emb,
    const float* __restrict__ thetas,
    const float* __restrict__ proto,
    const float* __restrict__ a0,
    const float* __restrict__ fa,
    const float* __restrict__ fb,
    float* __restrict__ out_emb,
    float* __restrict__ out_P,
    int B)
{
    __shared__ float sp[NC * D];
    __shared__ float sa0[NC * D];
    __shared__ float sfa[NC * FK * D];
    __shared__ float sfb[NC * FK * D];
    for (int i = threadIdx.x; i < NC * D; i += 256) { sp[i] = proto[i]; sa0[i] = a0[i]; }
    for (int i = threadIdx.x; i < NC * FK * D; i += 256) { sfa[i] = fa[i]; sfb[i] = fb[i]; }
    __syncthreads();

    const int b = blockIdx.x * 256 + threadIdx.x;
    if (b >= B) return;

    const float4* __restrict__ e4  = (const float4*)(emb + (size_t)b * D);
    const float4* sp4  = (const float4*)sp;
    const float4* sa04 = (const float4*)sa0;
    const float4* sfa4 = (const float4*)sfa;
    const float4* sfb4 = (const float4*)sfb;

    float sc[NC];
#pragma unroll
    for (int n = 0; n < NC; ++n) sc[n] = 0.0f;
#pragma unroll
    for (int i = 0; i < D / 4; ++i) {
        const float4 ev = e4[i];
#pragma unroll
        for (int n = 0; n < NC; ++n) {
            const float4 pv = sp4[n * (D / 4) + i];
            sc[n] = fmaf(ev.x, pv.x, sc[n]);
            sc[n] = fmaf(ev.y, pv.y, sc[n]);
            sc[n] = fmaf(ev.z, pv.z, sc[n]);
            sc[n] = fmaf(ev.w, pv.w, sc[n]);
        }
    }
    float mx = -1e30f;
#pragma unroll
    for (int n = 0; n < NC; ++n) { sc[n] *= 5.0f; mx = fmaxf(mx, sc[n]); }
    float sum = 0.0f;
#pragma unroll
    for (int n = 0; n < NC; ++n) { sc[n] = __expf(sc[n] - mx); sum += sc[n]; }
    const float inv = 1.0f / sum;
#pragma unroll
    for (int n = 0; n < NC; ++n) sc[n] *= inv;

    const float th = thetas[b];
    int m = (int)((th / TWO_PI_F) * (float)NMIN);
    m = m < 0 ? 0 : (m > NMIN - 1 ? NMIN - 1 : m);
    const float angle = (float)m * (TWO_PI_F / (float)(NMIN - 1));
    float c[FK], s[FK];
#pragma unroll
    for (int k = 0; k < FK; ++k) sincosf(angle * (float)(k + 1), &s[k], &c[k]);

    float4 acc[D / 4];
#pragma unroll
    for (int i = 0; i < D / 4; ++i) acc[i] = make_float4(0.f, 0.f, 0.f, 0.f);
#pragma unroll
    for (int n = 0; n < NC; ++n) {
        const float pw = sc[n];
#pragma unroll
        for (int i = 0; i < D / 4; ++i) {
            float4 v = sa04[n * (D / 4) + i];
#pragma unroll
            for (int k = 0; k < FK; ++k) {
                const float4 av = sfa4[(n * FK + k) * (D / 4) + i];
                const float4 bv = sfb4[(n * FK + k) * (D / 4) + i];
                v.x = fmaf(c[k], av.x, v.x); v.x = fmaf(s[k], bv.x, v.x);
                v.y = fmaf(c[k], av.y, v.y); v.y = fmaf(s[k], bv.y, v.y);
                v.z = fmaf(c[k], av.z, v.z); v.z = fmaf(s[k], bv.z, v.z);
                v.w = fmaf(c[k], av.w, v.w); v.w = fmaf(s[k], bv.w, v.w);
            }
            acc[i].x = fmaf(pw, v.x, acc[i].x);
            acc[i].y = fmaf(pw, v.y, acc[i].y);
            acc[i].z = fmaf(pw, v.z, acc[i].z);
            acc[i].w = fmaf(pw, v.w, acc[i].w);
        }
    }
    float4* o4 = (float4*)(out_emb + (size_t)b * D);
#pragma unroll
    for (int i = 0; i < D / 4; ++i) o4[i] = acc[i];
    float4* op = (float4*)(out_P + (size_t)b * NC);
    op[0] = make_float4(sc[0], sc[1], sc[2], sc[3]);
    op[1] = make_float4(sc[4], sc[5], sc[6], sc[7]);
}

extern "C" void kernel_launch(void* const* d_in, const int* in_sizes, int n_in,
                              void* d_out, int out_size, void* d_ws, size_t ws_size,
                              hipStream_t stream)
{
    const float* emb    = (const float*)d_in[0];
    const float* thetas = (const float*)d_in[1];
    const float* proto  = (const float*)d_in[2];
    const float* a0     = (const float*)d_in[3];
    const float* fa     = (const float*)d_in[4];
    const float* fb     = (const float*)d_in[5];

    const int B = in_sizes[0] / D;           // 131072
    float* out_emb = (float*)d_out;
    float* out_P   = (float*)d_out + (size_t)B * D;

    const size_t table_bytes = (size_t)NMIN * NC * D * sizeof(float); // ~2.95 MB

    if (ws_size >= table_bytes) {
        float* T = (float*)d_ws;
        build_table_kernel<<<NMIN, 256, 0, stream>>>(a0, fa, fb, T);
        // 8 lanes per item: B*8 threads total
        const long long total_threads = (long long)B * 8;
        const int blocks = (int)((total_threads + 255) / 256);
        mix_kernel8<<<blocks, 256, 0, stream>>>(emb, thetas, proto, T, out_emb, out_P, B);
    } else {
        const int blocks = (B + 255) / 256;
        fused_fallback<<<blocks, 256, 0, stream>>>(emb, thetas, proto, a0, fa, fb,
                                                   out_emb, out_P, B);
    }
}